// Round 8
// baseline (219.838 us; speedup 1.0000x reference)
//
#include <hip/hip_runtime.h>
#include <math.h>

typedef __attribute__((ext_vector_type(8)))  short  short8;
typedef __attribute__((ext_vector_type(16))) float  float16;

#define TWO_PI_OVER_32 0.19634954084936207f

static __device__ __forceinline__ unsigned short f2bf(float f) {
    unsigned int u = __float_as_uint(f);
    u = (u + 0x7FFFu + ((u >> 16) & 1u)) >> 16;
    return (unsigned short)u;
}
static __device__ __forceinline__ float bf2f(unsigned short s) {
    return __uint_as_float(((unsigned int)s) << 16);
}

// async global->LDS 16B: per-lane global src, wave-uniform LDS base + lane*16
static __device__ __forceinline__ void g2l16(const void* g, void* l) {
    __builtin_amdgcn_global_load_lds(
        (const __attribute__((address_space(1))) unsigned int*)g,
        (__attribute__((address_space(3))) unsigned int*)l, 16, 0, 0);
}

// ---------------------------------------------------------------------------
// K_prepx: fused x-conversion + weight-side preprocessing.
//  blocks 0..4095: x fp32 (b,ci,r,c) -> xb bf16 granules [b][ci>>3][r][c][ci&7]
//  blocks 4096..4351 (row mode, p): Drow[p][45]; wt bf16 granules; Vb bf16
//  blocks 4352..4607 (col mode, c): Dcol[c][45]
//  block 4096 zeroes accum[0..2] + ticket.
// ---------------------------------------------------------------------------
__global__ __launch_bounds__(256) void k_prepx(const float* __restrict__ x,
                                               unsigned short* __restrict__ xb,
                                               const float* __restrict__ w,
                                               unsigned short* __restrict__ wt,
                                               unsigned short* __restrict__ Vb,
                                               float* __restrict__ Drow,
                                               float* __restrict__ Dcol,
                                               float* __restrict__ accum) {
    int tid = threadIdx.x;
    if (blockIdx.x < 4096) {
        int g = blockIdx.x * 256 + tid;            // 1,048,576 granules
        int c = g & 31, r = (g >> 5) & 31, cig = (g >> 10) & 31, b = g >> 15;
        const float* xp = x + ((b * 256 + cig * 8) * 32 + r) * 32 + c;
        union { unsigned short u[8]; uint4 v; } pk;
        #pragma unroll
        for (int u = 0; u < 8; ++u) pk.u[u] = f2bf(xp[u * 1024]);
        ((uint4*)xb)[g] = pk.v;
        return;
    }
    __shared__ float sdata[45];
    __shared__ float ws2[256 * 9];
    int blk = blockIdx.x - 4096, lane = tid & 63;
    bool colmode = blk >= 256;
    int pc = blk & 255;
    if (blk == 0 && tid < 4) accum[tid] = 0.f;     // sums + ticket
    if (tid < 45) sdata[tid] = 0.f;

    int p = colmode ? tid : pc;
    int c = colmode ? pc : tid;
    float w9[9];
    #pragma unroll
    for (int t = 0; t < 9; ++t) w9[t] = w[(p * 256 + c) * 9 + t];
    if (!colmode) {
        #pragma unroll
        for (int t = 0; t < 9; ++t) ws2[tid * 9 + t] = w9[t];
    }
    __syncthreads();

    int idx = 0;
    for (int ta = 0; ta < 9; ++ta)
        for (int tb = ta; tb < 9; ++tb) {
            float v = w9[ta] * w9[tb];
            #pragma unroll
            for (int off = 32; off > 0; off >>= 1) v += __shfl_down(v, off);
            if (lane == 0) atomicAdd(&sdata[idx], v);
            ++idx;
        }
    __syncthreads();
    if (tid < 45) (colmode ? Dcol : Drow)[pc * 45 + tid] = sdata[tid];

    if (!colmode) {
        // wt granule layout [t][ci>>3][co][ci&7]; this block covers co=p, all ci
        #pragma unroll
        for (int t = 0; t < 9; ++t)
            wt[t * 65536 + (c >> 3) * 2048 + p * 8 + (c & 7)] = f2bf(w9[t]);
        // Vb granules [row=p*10+ta][cig 32][8ci], tap slot 9 zeroed
        if (tid < 320) {
            int ta = tid >> 5, cig = tid & 31;
            union { unsigned short u[8]; uint4 v; } pk;
            #pragma unroll
            for (int u = 0; u < 8; ++u)
                pk.u[u] = (ta < 9) ? f2bf(ws2[(cig * 8 + u) * 9 + ta]) : (unsigned short)0;
            ((uint4*)Vb)[(p * 10 + ta) * 32 + cig] = pk.v;
        }
    }
}

// ---------------------------------------------------------------------------
// K1: blocks 0..511: conv via implicit GEMM (dbuf LDS, 1 barrier/kc);
//     blocks 512..721: Gram G = V V^T (2560x2560, K=256), upper tiles.
// ---------------------------------------------------------------------------
__global__ __launch_bounds__(256, 2) void k_conv(const unsigned short* __restrict__ xb,
                                                 const unsigned short* __restrict__ wt,
                                                 const float* __restrict__ bias,
                                                 const unsigned short* __restrict__ Vb,
                                                 unsigned short* __restrict__ Gb,
                                                 float* __restrict__ y) {
    __shared__ unsigned short xs[2][640 * 8];   // [slot 10][cig 2][col 32][8ci] 2x10240 B
    __shared__ unsigned short wsm[2][1152 * 8]; // [t 9][cig 2][co 64][8ci]     2x18432 B

    const int tid  = threadIdx.x;
    const int lane = tid & 63;
    const int half = lane >> 5;
    const int m    = lane & 31;

    if (blockIdx.x >= 512) {
        // ---------------- Gram path ----------------
        int blk = blockIdx.x - 512, I = 0;
        while (blk >= 20 - I) { blk -= 20 - I; ++I; }
        int J = I + blk;
        const int wave = tid >> 6;
        const int wm = wave >> 1, wn = wave & 1;
        const int row0 = I * 128 + wm * 64;
        const int col0 = J * 128 + wn * 64;

        float16 acc[2][2];
        #pragma unroll
        for (int i = 0; i < 2; ++i)
            #pragma unroll
            for (int j = 0; j < 2; ++j)
                #pragma unroll
                for (int r = 0; r < 16; ++r) acc[i][j][r] = 0.f;

        const short8* vb = (const short8*)Vb;
        for (int kc = 0; kc < 16; ++kc) {
            int cig = kc * 2 + half;
            short8 a0 = vb[(row0 + m) * 32 + cig];
            short8 a1 = vb[(row0 + 32 + m) * 32 + cig];
            short8 b0 = vb[(col0 + m) * 32 + cig];
            short8 b1 = vb[(col0 + 32 + m) * 32 + cig];
            acc[0][0] = __builtin_amdgcn_mfma_f32_32x32x16_bf16(a0, b0, acc[0][0], 0, 0, 0);
            acc[0][1] = __builtin_amdgcn_mfma_f32_32x32x16_bf16(a0, b1, acc[0][1], 0, 0, 0);
            acc[1][0] = __builtin_amdgcn_mfma_f32_32x32x16_bf16(a1, b0, acc[1][0], 0, 0, 0);
            acc[1][1] = __builtin_amdgcn_mfma_f32_32x32x16_bf16(a1, b1, acc[1][1], 0, 0, 0);
        }
        #pragma unroll
        for (int i = 0; i < 2; ++i)
            #pragma unroll
            for (int j = 0; j < 2; ++j)
                #pragma unroll
                for (int reg = 0; reg < 16; ++reg) {
                    int crow = (reg & 3) + 8 * (reg >> 2) + 4 * half;
                    Gb[(row0 + i * 32 + crow) * 2560 + col0 + j * 32 + m] =
                        f2bf(acc[i][j][reg]);
                }
        return;
    }

    // ---------------- conv path ----------------
    const int wv   = tid >> 6;               // wave 0..3 -> row pair
    const int id    = blockIdx.x;
    const int xcd   = id & 7;
    const int local = id >> 3;
    const int b     = xcd * 4 + (local >> 4);
    const int rem   = local & 15;
    const int co0   = (rem & 3) * 64;
    const int r0    = (rem >> 2) * 8;

    float16 acc[2][2];
    #pragma unroll
    for (int i = 0; i < 2; ++i)
        #pragma unroll
        for (int ns = 0; ns < 2; ++ns)
            #pragma unroll
            for (int r = 0; r < 16; ++r) acc[i][ns][r] = 0.f;

    const uint4* xbv = (const uint4*)xb;
    const uint4* wtv = (const uint4*)wt;

    const int cigl = lane >> 5;              // x staging: lane -> (cig, col)
    const int coll = lane & 31;

    auto stage = [&](int buf, int kc) {
        uint4* xd = (uint4*)xs[buf];
        uint4* wd = (uint4*)wsm[buf];
        #pragma unroll
        for (int ch = wv; ch < 28; ch += 4) {
            if (ch < 10) {
                int gr = (r0 + ch + 31) & 31;
                g2l16(&xbv[((b * 32 + kc * 2 + cigl) * 32 + gr) * 32 + coll],
                      &xd[ch * 64]);
            } else {
                int wc = ch - 10;
                int t = wc >> 1, cig = wc & 1;
                g2l16(&wtv[t * 8192 + (kc * 2 + cig) * 256 + co0 + lane],
                      &wd[wc * 64]);
            }
        }
    };

    auto compute = [&](int buf) {
        const short8* xsl = (const short8*)xs[buf];
        const short8* wsl = (const short8*)wsm[buf];
        #pragma unroll
        for (int t = 0; t < 9; ++t) {
            const int atv = t / 3, btv = t % 3;
            short8 a0 = wsl[(t * 2 + half) * 64 + m];
            short8 a1 = wsl[(t * 2 + half) * 64 + 32 + m];
            #pragma unroll
            for (int ns = 0; ns < 2; ++ns) {
                int slot = wv * 2 + ns + atv;          // 0..9
                short8 bf = xsl[(slot * 2 + half) * 32 + ((m + btv + 31) & 31)];
                acc[0][ns] = __builtin_amdgcn_mfma_f32_32x32x16_bf16(a0, bf, acc[0][ns], 0, 0, 0);
                acc[1][ns] = __builtin_amdgcn_mfma_f32_32x32x16_bf16(a1, bf, acc[1][ns], 0, 0, 0);
            }
        }
    };

    stage(0, 0);
    #pragma unroll 1
    for (int kc2 = 0; kc2 < 8; ++kc2) {
        __syncthreads();                     // drains stage into buf 0
        stage(1, 2 * kc2 + 1);
        compute(0);
        __syncthreads();                     // drains stage into buf 1
        if (kc2 < 7) stage(0, 2 * kc2 + 2);
        compute(1);
    }

    // epilogue: C layout: col=lane&31, row=(reg&3)+8*(reg>>2)+4*half
    #pragma unroll
    for (int i = 0; i < 2; ++i) {
        #pragma unroll
        for (int ns = 0; ns < 2; ++ns) {
            int r = r0 + wv * 2 + ns;
            #pragma unroll
            for (int reg = 0; reg < 16; ++reg) {
                int crow = (reg & 3) + 8 * (reg >> 2) + 4 * half;
                int co = co0 + i * 32 + crow;
                y[(b * 256 + co) * 1024 + r * 32 + m] = acc[i][ns][reg] + bias[co];
            }
        }
    }
}

// ---------------------------------------------------------------------------
// K_loss: blocks 0..543 = Row/Col loss per bin; blocks 544..799 = AngLoss.
// AngLoss closed form: ReS = {17,0,1,0,1} ->
//   S_pq = 32 * sum_da [ 17*sum_j g_j^2 + 2*(g0g2+g1g3+g2g4+g0g4) ]
// Last block (ticket==799) computes final L into out[8388608].
// ---------------------------------------------------------------------------
__global__ __launch_bounds__(256) void k_loss(const float* __restrict__ Drow,
                                              const float* __restrict__ Dcol,
                                              const unsigned short* __restrict__ Gb,
                                              float* __restrict__ accum,
                                              float* __restrict__ out) {
    __shared__ union {
        struct { float coef[45]; float red[2]; } rc;
        struct { unsigned short gs[9 * 2560]; float red; } ang;
    } sh;
    int tid = threadIdx.x;

    if (blockIdx.x < 544) {
        int bin = blockIdx.x;
        int u = bin / 17, v = bin % 17;
        if (tid < 2) sh.rc.red[tid] = 0.f;
        if (tid < 45) {
            int idx = 0, TA = 0, TB = 0;
            for (int ta = 0; ta < 9; ++ta)
                for (int tb = ta; tb < 9; ++tb) {
                    if (idx == tid) { TA = ta; TB = tb; }
                    ++idx;
                }
            int da = TA / 3 - TB / 3;
            int db = TA % 3 - TB % 3;
            float cth = cosf(TWO_PI_OVER_32 * (float)(u * da + v * db));
            sh.rc.coef[tid] = (TA == TB) ? 1.f : 2.f * cth;
        }
        __syncthreads();

        float s1 = 0.f, s2 = 0.f;
        const float* dr = Drow + tid * 45;
        const float* dc = Dcol + tid * 45;
        #pragma unroll
        for (int i = 0; i < 45; ++i) {
            s1 += sh.rc.coef[i] * dr[i];
            s2 += sh.rc.coef[i] * dc[i];
        }
        float e1 = sqrtf(fmaxf(s1, 0.f)) - 1.f; e1 *= e1;
        float e2 = sqrtf(fmaxf(s2, 0.f)) - 1.f; e2 *= e2;
        #pragma unroll
        for (int off = 32; off > 0; off >>= 1) {
            e1 += __shfl_down(e1, off);
            e2 += __shfl_down(e2, off);
        }
        if ((tid & 63) == 0) { atomicAdd(&sh.rc.red[0], e1); atomicAdd(&sh.rc.red[1], e2); }
        __syncthreads();
        if (tid == 0) { atomicAdd(&accum[0], sh.rc.red[0]); atomicAdd(&accum[1], sh.rc.red[1]); }
    } else {
        int p = blockIdx.x - 544;
        if (tid == 0) sh.ang.red = 0.f;
        uint4* gsv = (uint4*)sh.ang.gs;
        const uint4* gbv = (const uint4*)Gb;
        for (int i = tid; i < 2880; i += 256) {
            int rr = i / 320, cc = i - rr * 320;
            gsv[i] = gbv[(p * 10 + rr) * 320 + cc];
        }
        __syncthreads();

        int q = tid;
        float S = 0.f;
        if (q > p) {
            float g5[5][5];
            #pragma unroll
            for (int i = 0; i < 5; ++i)
                #pragma unroll
                for (int j = 0; j < 5; ++j) g5[i][j] = 0.f;
            #pragma unroll
            for (int ta = 0; ta < 9; ++ta)
                #pragma unroll
                for (int tb = 0; tb < 9; ++tb) {
                    float c = bf2f(sh.ang.gs[ta * 2560 + q * 10 + tb]);
                    g5[ta / 3 - tb / 3 + 2][ta % 3 - tb % 3 + 2] += c;
                }
            // ReS = {17,0,1,0,1}
            #pragma unroll
            for (int da = 0; da < 5; ++da) {
                const float* g = g5[da];
                float sq = g[0]*g[0] + g[1]*g[1] + g[2]*g[2] + g[3]*g[3] + g[4]*g[4];
                float cr = g[0]*g[2] + g[1]*g[3] + g[2]*g[4] + g[0]*g[4];
                S += 17.f * sq + 2.f * cr;
            }
            S *= 32.f;
        }
        #pragma unroll
        for (int off = 32; off > 0; off >>= 1) S += __shfl_down(S, off);
        if ((tid & 63) == 0) atomicAdd(&sh.ang.red, S);
        __syncthreads();
        if (tid == 0) atomicAdd(&accum[2], sh.ang.red);
    }

    // last-block finalization
    __threadfence();
    if (tid == 0) {
        unsigned int old = atomicAdd((unsigned int*)(accum + 3), 1u);
        if (old == 799u) {
            float row = atomicAdd(&accum[0], 0.f);
            float col = atomicAdd(&accum[1], 0.f);
            float ang = atomicAdd(&accum[2], 0.f);
            out[8388608] = row / 544.f + col / 544.f + ang / (544.f * 32640.f);
        }
    }
}

// ---------------------------------------------------------------------------
extern "C" void kernel_launch(void* const* d_in, const int* in_sizes, int n_in,
                              void* d_out, int out_size, void* d_ws, size_t ws_size,
                              hipStream_t stream) {
    const float* x    = (const float*)d_in[0];   // (32,256,32,32)
    const float* w    = (const float*)d_in[1];   // (256,256,3,3)
    const float* bias = (const float*)d_in[2];   // (256,)
    float* out = (float*)d_out;

    char* ws = (char*)d_ws;
    unsigned short* wt = (unsigned short*)ws;               //  1,179,648 B
    unsigned short* xb = (unsigned short*)(ws + 1179648);   // 16,777,216 B
    unsigned short* Vb = (unsigned short*)(ws + 17956864);  //  1,310,720 B
    float* Drow  = (float*)(ws + 19267584);                 //     46,080 B
    float* Dcol  = (float*)(ws + 19313664);                 //     46,080 B
    float* accum = (float*)(ws + 19359744);                 //         32 B
    unsigned short* Gb = (unsigned short*)(ws + 19392512);  // 13,107,200 B (no alias: gram runs with conv)

    k_prepx <<<4608, 256, 0, stream>>>(x, xb, w, wt, Vb, Drow, Dcol, accum);
    k_conv  <<<722, 256, 0, stream>>>(xb, wt, bias, Vb, Gb, out);
    k_loss  <<<800, 256, 0, stream>>>(Drow, Dcol, Gb, accum, out);
}

// Round 9
// 170.539 us; speedup vs baseline: 1.2891x; 1.2891x over previous
//
#include <hip/hip_runtime.h>
#include <math.h>

typedef __attribute__((ext_vector_type(8)))  short  short8;
typedef __attribute__((ext_vector_type(16))) float  float16;

#define TWO_PI_OVER_32 0.19634954084936207f

static __device__ __forceinline__ unsigned short f2bf(float f) {
    unsigned int u = __float_as_uint(f);
    u = (u + 0x7FFFu + ((u >> 16) & 1u)) >> 16;
    return (unsigned short)u;
}
static __device__ __forceinline__ float bf2f(unsigned short s) {
    return __uint_as_float(((unsigned int)s) << 16);
}

// async global->LDS 16B: per-lane global src, wave-uniform LDS base + lane*16
static __device__ __forceinline__ void g2l16(const void* g, void* l) {
    __builtin_amdgcn_global_load_lds(
        (const __attribute__((address_space(1))) unsigned int*)g,
        (__attribute__((address_space(3))) unsigned int*)l, 16, 0, 0);
}

// ---------------------------------------------------------------------------
// K_prepx: fused x-conversion + weight-side preprocessing.
//  blocks 0..4095: x fp32 (b,ci,r,c) -> xb bf16 granules [b][ci>>3][r][c][ci&7]
//  blocks 4096..4351 (row mode, p): Drow[p][45]; wt bf16 granules; Vb bf16
//  blocks 4352..4607 (col mode, c): Dcol[c][45]
//  block 4096 zeroes accum.
// ---------------------------------------------------------------------------
__global__ __launch_bounds__(256) void k_prepx(const float* __restrict__ x,
                                               unsigned short* __restrict__ xb,
                                               const float* __restrict__ w,
                                               unsigned short* __restrict__ wt,
                                               unsigned short* __restrict__ Vb,
                                               float* __restrict__ Drow,
                                               float* __restrict__ Dcol,
                                               float* __restrict__ accum) {
    int tid = threadIdx.x;
    if (blockIdx.x < 4096) {
        int g = blockIdx.x * 256 + tid;            // 1,048,576 granules
        int c = g & 31, r = (g >> 5) & 31, cig = (g >> 10) & 31, b = g >> 15;
        const float* xp = x + ((b * 256 + cig * 8) * 32 + r) * 32 + c;
        union { unsigned short u[8]; uint4 v; } pk;
        #pragma unroll
        for (int u = 0; u < 8; ++u) pk.u[u] = f2bf(xp[u * 1024]);
        ((uint4*)xb)[g] = pk.v;
        return;
    }
    __shared__ float sdata[45];
    __shared__ float ws2[256 * 9];
    int blk = blockIdx.x - 4096, lane = tid & 63;
    bool colmode = blk >= 256;
    int pc = blk & 255;
    if (blk == 0 && tid < 4) accum[tid] = 0.f;
    if (tid < 45) sdata[tid] = 0.f;

    int p = colmode ? tid : pc;
    int c = colmode ? pc : tid;
    float w9[9];
    #pragma unroll
    for (int t = 0; t < 9; ++t) w9[t] = w[(p * 256 + c) * 9 + t];
    if (!colmode) {
        #pragma unroll
        for (int t = 0; t < 9; ++t) ws2[tid * 9 + t] = w9[t];
    }
    __syncthreads();

    int idx = 0;
    for (int ta = 0; ta < 9; ++ta)
        for (int tb = ta; tb < 9; ++tb) {
            float v = w9[ta] * w9[tb];
            #pragma unroll
            for (int off = 32; off > 0; off >>= 1) v += __shfl_down(v, off);
            if (lane == 0) atomicAdd(&sdata[idx], v);
            ++idx;
        }
    __syncthreads();
    if (tid < 45) (colmode ? Dcol : Drow)[pc * 45 + tid] = sdata[tid];

    if (!colmode) {
        // wt granule layout [t][ci>>3][co][ci&7]; this block covers co=p, all ci
        #pragma unroll
        for (int t = 0; t < 9; ++t)
            wt[t * 65536 + (c >> 3) * 2048 + p * 8 + (c & 7)] = f2bf(w9[t]);
        // Vb granules [row=p*10+ta][cig 32][8ci], tap slot 9 zeroed
        if (tid < 320) {
            int ta = tid >> 5, cig = tid & 31;
            union { unsigned short u[8]; uint4 v; } pk;
            #pragma unroll
            for (int u = 0; u < 8; ++u)
                pk.u[u] = (ta < 9) ? f2bf(ws2[(cig * 8 + u) * 9 + ta]) : (unsigned short)0;
            ((uint4*)Vb)[(p * 10 + ta) * 32 + cig] = pk.v;
        }
    }
}

// ---------------------------------------------------------------------------
// K1: blocks 0..511: conv via implicit GEMM (dbuf LDS, 1 barrier/kc);
//     blocks 512..721: Gram G = V V^T (2560x2560, K=256), upper tiles.
// ---------------------------------------------------------------------------
__global__ __launch_bounds__(256, 2) void k_conv(const unsigned short* __restrict__ xb,
                                                 const unsigned short* __restrict__ wt,
                                                 const float* __restrict__ bias,
                                                 const unsigned short* __restrict__ Vb,
                                                 unsigned short* __restrict__ Gb,
                                                 float* __restrict__ y) {
    __shared__ unsigned short xs[2][640 * 8];   // [slot 10][cig 2][col 32][8ci] 2x10240 B
    __shared__ unsigned short wsm[2][1152 * 8]; // [t 9][cig 2][co 64][8ci]     2x18432 B

    const int tid  = threadIdx.x;
    const int lane = tid & 63;
    const int half = lane >> 5;
    const int m    = lane & 31;

    if (blockIdx.x >= 512) {
        // ---------------- Gram path ----------------
        int blk = blockIdx.x - 512, I = 0;
        while (blk >= 20 - I) { blk -= 20 - I; ++I; }
        int J = I + blk;
        const int wave = tid >> 6;
        const int wm = wave >> 1, wn = wave & 1;
        const int row0 = I * 128 + wm * 64;
        const int col0 = J * 128 + wn * 64;

        float16 acc[2][2];
        #pragma unroll
        for (int i = 0; i < 2; ++i)
            #pragma unroll
            for (int j = 0; j < 2; ++j)
                #pragma unroll
                for (int r = 0; r < 16; ++r) acc[i][j][r] = 0.f;

        const short8* vb = (const short8*)Vb;
        for (int kc = 0; kc < 16; ++kc) {
            int cig = kc * 2 + half;
            short8 a0 = vb[(row0 + m) * 32 + cig];
            short8 a1 = vb[(row0 + 32 + m) * 32 + cig];
            short8 b0 = vb[(col0 + m) * 32 + cig];
            short8 b1 = vb[(col0 + 32 + m) * 32 + cig];
            acc[0][0] = __builtin_amdgcn_mfma_f32_32x32x16_bf16(a0, b0, acc[0][0], 0, 0, 0);
            acc[0][1] = __builtin_amdgcn_mfma_f32_32x32x16_bf16(a0, b1, acc[0][1], 0, 0, 0);
            acc[1][0] = __builtin_amdgcn_mfma_f32_32x32x16_bf16(a1, b0, acc[1][0], 0, 0, 0);
            acc[1][1] = __builtin_amdgcn_mfma_f32_32x32x16_bf16(a1, b1, acc[1][1], 0, 0, 0);
        }
        #pragma unroll
        for (int i = 0; i < 2; ++i)
            #pragma unroll
            for (int j = 0; j < 2; ++j)
                #pragma unroll
                for (int reg = 0; reg < 16; ++reg) {
                    int crow = (reg & 3) + 8 * (reg >> 2) + 4 * half;
                    Gb[(row0 + i * 32 + crow) * 2560 + col0 + j * 32 + m] =
                        f2bf(acc[i][j][reg]);
                }
        return;
    }

    // ---------------- conv path ----------------
    const int wv   = tid >> 6;               // wave 0..3 -> row pair
    const int id    = blockIdx.x;
    const int xcd   = id & 7;
    const int local = id >> 3;
    const int b     = xcd * 4 + (local >> 4);
    const int rem   = local & 15;
    const int co0   = (rem & 3) * 64;
    const int r0    = (rem >> 2) * 8;

    float16 acc[2][2];
    #pragma unroll
    for (int i = 0; i < 2; ++i)
        #pragma unroll
        for (int ns = 0; ns < 2; ++ns)
            #pragma unroll
            for (int r = 0; r < 16; ++r) acc[i][ns][r] = 0.f;

    const uint4* xbv = (const uint4*)xb;
    const uint4* wtv = (const uint4*)wt;

    const int cigl = lane >> 5;              // x staging: lane -> (cig, col)
    const int coll = lane & 31;

    auto stage = [&](int buf, int kc) {
        uint4* xd = (uint4*)xs[buf];
        uint4* wd = (uint4*)wsm[buf];
        #pragma unroll
        for (int ch = wv; ch < 28; ch += 4) {
            if (ch < 10) {
                int gr = (r0 + ch + 31) & 31;
                g2l16(&xbv[((b * 32 + kc * 2 + cigl) * 32 + gr) * 32 + coll],
                      &xd[ch * 64]);
            } else {
                int wc = ch - 10;
                int t = wc >> 1, cig = wc & 1;
                g2l16(&wtv[t * 8192 + (kc * 2 + cig) * 256 + co0 + lane],
                      &wd[wc * 64]);
            }
        }
    };

    auto compute = [&](int buf) {
        const short8* xsl = (const short8*)xs[buf];
        const short8* wsl = (const short8*)wsm[buf];
        #pragma unroll
        for (int t = 0; t < 9; ++t) {
            const int atv = t / 3, btv = t % 3;
            short8 a0 = wsl[(t * 2 + half) * 64 + m];
            short8 a1 = wsl[(t * 2 + half) * 64 + 32 + m];
            #pragma unroll
            for (int ns = 0; ns < 2; ++ns) {
                int slot = wv * 2 + ns + atv;          // 0..9
                short8 bf = xsl[(slot * 2 + half) * 32 + ((m + btv + 31) & 31)];
                acc[0][ns] = __builtin_amdgcn_mfma_f32_32x32x16_bf16(a0, bf, acc[0][ns], 0, 0, 0);
                acc[1][ns] = __builtin_amdgcn_mfma_f32_32x32x16_bf16(a1, bf, acc[1][ns], 0, 0, 0);
            }
        }
    };

    stage(0, 0);
    #pragma unroll 1
    for (int kc2 = 0; kc2 < 8; ++kc2) {
        __syncthreads();                     // drains stage into buf 0
        stage(1, 2 * kc2 + 1);
        compute(0);
        __syncthreads();                     // drains stage into buf 1
        if (kc2 < 7) stage(0, 2 * kc2 + 2);
        compute(1);
    }

    // epilogue: C layout: col=lane&31, row=(reg&3)+8*(reg>>2)+4*half
    #pragma unroll
    for (int i = 0; i < 2; ++i) {
        #pragma unroll
        for (int ns = 0; ns < 2; ++ns) {
            int r = r0 + wv * 2 + ns;
            #pragma unroll
            for (int reg = 0; reg < 16; ++reg) {
                int crow = (reg & 3) + 8 * (reg >> 2) + 4 * half;
                int co = co0 + i * 32 + crow;
                y[(b * 256 + co) * 1024 + r * 32 + m] = acc[i][ns][reg] + bias[co];
            }
        }
    }
}

// ---------------------------------------------------------------------------
// K_loss: blocks 0..543 = Row/Col loss per bin; blocks 544..799 = AngLoss.
// AngLoss closed form: ReS = {17,0,1,0,1} ->
//   S_pq = 32 * sum_da [ 17*sum_j g_j^2 + 2*(g0g2+g1g3+g2g4+g0g4) ]
// NO device fences here (threadfence = L2 flush on multi-XCD, ~40us for 800
// blocks — measured round 8). Finalization in a separate kernel.
// ---------------------------------------------------------------------------
__global__ __launch_bounds__(256) void k_loss(const float* __restrict__ Drow,
                                              const float* __restrict__ Dcol,
                                              const unsigned short* __restrict__ Gb,
                                              float* __restrict__ accum) {
    __shared__ union {
        struct { float coef[45]; float red[2]; } rc;
        struct { unsigned short gs[9 * 2560]; float red; } ang;
    } sh;
    int tid = threadIdx.x;

    if (blockIdx.x < 544) {
        int bin = blockIdx.x;
        int u = bin / 17, v = bin % 17;
        if (tid < 2) sh.rc.red[tid] = 0.f;
        if (tid < 45) {
            int idx = 0, TA = 0, TB = 0;
            for (int ta = 0; ta < 9; ++ta)
                for (int tb = ta; tb < 9; ++tb) {
                    if (idx == tid) { TA = ta; TB = tb; }
                    ++idx;
                }
            int da = TA / 3 - TB / 3;
            int db = TA % 3 - TB % 3;
            float cth = cosf(TWO_PI_OVER_32 * (float)(u * da + v * db));
            sh.rc.coef[tid] = (TA == TB) ? 1.f : 2.f * cth;
        }
        __syncthreads();

        float s1 = 0.f, s2 = 0.f;
        const float* dr = Drow + tid * 45;
        const float* dc = Dcol + tid * 45;
        #pragma unroll
        for (int i = 0; i < 45; ++i) {
            s1 += sh.rc.coef[i] * dr[i];
            s2 += sh.rc.coef[i] * dc[i];
        }
        float e1 = sqrtf(fmaxf(s1, 0.f)) - 1.f; e1 *= e1;
        float e2 = sqrtf(fmaxf(s2, 0.f)) - 1.f; e2 *= e2;
        #pragma unroll
        for (int off = 32; off > 0; off >>= 1) {
            e1 += __shfl_down(e1, off);
            e2 += __shfl_down(e2, off);
        }
        if ((tid & 63) == 0) { atomicAdd(&sh.rc.red[0], e1); atomicAdd(&sh.rc.red[1], e2); }
        __syncthreads();
        if (tid == 0) { atomicAdd(&accum[0], sh.rc.red[0]); atomicAdd(&accum[1], sh.rc.red[1]); }
    } else {
        int p = blockIdx.x - 544;
        if (tid == 0) sh.ang.red = 0.f;
        uint4* gsv = (uint4*)sh.ang.gs;
        const uint4* gbv = (const uint4*)Gb;
        for (int i = tid; i < 2880; i += 256) {
            int rr = i / 320, cc = i - rr * 320;
            gsv[i] = gbv[(p * 10 + rr) * 320 + cc];
        }
        __syncthreads();

        int q = tid;
        float S = 0.f;
        if (q > p) {
            float g5[5][5];
            #pragma unroll
            for (int i = 0; i < 5; ++i)
                #pragma unroll
                for (int j = 0; j < 5; ++j) g5[i][j] = 0.f;
            #pragma unroll
            for (int ta = 0; ta < 9; ++ta)
                #pragma unroll
                for (int tb = 0; tb < 9; ++tb) {
                    float c = bf2f(sh.ang.gs[ta * 2560 + q * 10 + tb]);
                    g5[ta / 3 - tb / 3 + 2][ta % 3 - tb % 3 + 2] += c;
                }
            // ReS = {17,0,1,0,1}
            #pragma unroll
            for (int da = 0; da < 5; ++da) {
                const float* g = g5[da];
                float sq = g[0]*g[0] + g[1]*g[1] + g[2]*g[2] + g[3]*g[3] + g[4]*g[4];
                float cr = g[0]*g[2] + g[1]*g[3] + g[2]*g[4] + g[0]*g[4];
                S += 17.f * sq + 2.f * cr;
            }
            S *= 32.f;
        }
        #pragma unroll
        for (int off = 32; off > 0; off >>= 1) S += __shfl_down(S, off);
        if ((tid & 63) == 0) atomicAdd(&sh.ang.red, S);
        __syncthreads();
        if (tid == 0) atomicAdd(&accum[2], sh.ang.red);
    }
}

// ---------------------------------------------------------------------------
// K5: finalize L (kernel boundary provides visibility of k_loss's atomics)
// ---------------------------------------------------------------------------
__global__ void k_fin(const float* __restrict__ accum, float* __restrict__ out) {
    if (threadIdx.x == 0 && blockIdx.x == 0) {
        float row = accum[0], col = accum[1], ang = accum[2];
        out[8388608] = row / 544.f + col / 544.f + ang / (544.f * 32640.f);
    }
}

// ---------------------------------------------------------------------------
extern "C" void kernel_launch(void* const* d_in, const int* in_sizes, int n_in,
                              void* d_out, int out_size, void* d_ws, size_t ws_size,
                              hipStream_t stream) {
    const float* x    = (const float*)d_in[0];   // (32,256,32,32)
    const float* w    = (const float*)d_in[1];   // (256,256,3,3)
    const float* bias = (const float*)d_in[2];   // (256,)
    float* out = (float*)d_out;

    char* ws = (char*)d_ws;
    unsigned short* wt = (unsigned short*)ws;               //  1,179,648 B
    unsigned short* xb = (unsigned short*)(ws + 1179648);   // 16,777,216 B
    unsigned short* Vb = (unsigned short*)(ws + 17956864);  //  1,310,720 B
    float* Drow  = (float*)(ws + 19267584);                 //     46,080 B
    float* Dcol  = (float*)(ws + 19313664);                 //     46,080 B
    float* accum = (float*)(ws + 19359744);                 //         32 B
    unsigned short* Gb = (unsigned short*)(ws + 19392512);  // 13,107,200 B (no alias: gram runs with conv)

    k_prepx <<<4608, 256, 0, stream>>>(x, xb, w, wt, Vb, Drow, Dcol, accum);
    k_conv  <<<722, 256, 0, stream>>>(xb, wt, bias, Vb, Gb, out);
    k_loss  <<<800, 256, 0, stream>>>(Drow, Dcol, Gb, accum);
    k_fin   <<<1, 64, 0, stream>>>(accum, out);
}